// Round 2
// baseline (813.300 us; speedup 1.0000x reference)
//
#include <hip/hip_runtime.h>

typedef unsigned short ushort_t;
typedef unsigned int   uint32;
typedef __attribute__((ext_vector_type(8))) short short8;   // 8 bf16 (4 VGPRs)
typedef __attribute__((ext_vector_type(4))) float f32x4;    // MFMA acc

// ---------------- problem constants ----------------
#define B_     8
#define CIN    512
#define HFM    10
#define WFM    25
#define CF     64
#define NANCH  2784          // N
#define NM     2783          // N-1
#define NMPAD  2816          // N-1 padded to 128
#define D_     640           // CF*HFM
#define D2     1280
#define ALEN   77
#define M_     (B_*NANCH)    // 22272

// counted-vmcnt pipeline helpers (T4): never drain vmcnt to 0 in the main loop
#define VMCNT(N)   asm volatile("s_waitcnt vmcnt(" #N ")" ::: "memory")
#define S_BARRIER() do { __builtin_amdgcn_s_barrier(); __builtin_amdgcn_sched_barrier(0); } while (0)

__device__ __forceinline__ ushort_t f2bf(float f) {
    uint32 u = __float_as_uint(f);
    u += 0x7fffu + ((u >> 16) & 1u);     // RNE
    return (ushort_t)(u >> 16);
}
__device__ __forceinline__ float bf2f(ushort_t h) {
    return __uint_as_float(((uint32)h) << 16);
}

__device__ __forceinline__ void gload16(const ushort_t* g, ushort_t* l) {
    __builtin_amdgcn_global_load_lds(
        (const __attribute__((address_space(1))) void*)g,
        (__attribute__((address_space(3))) void*)l, 16, 0, 0);
}

// ============ 1x1 conv ============
__global__ __launch_bounds__(256) void conv_feat_k(const float* __restrict__ x,
    const float* __restrict__ w, const float* __restrict__ bias,
    float* __restrict__ feat)
{
    int t = blockIdx.x * 256 + threadIdx.x;
    if (t >= B_ * CF * HFM * WFM) return;
    int pos = t % (HFM * WFM);
    int f   = (t / (HFM * WFM)) % CF;
    int b   = t / (CF * HFM * WFM);
    const float* xp = x + (size_t)b * CIN * HFM * WFM + pos;
    const float* wp = w + (size_t)f * CIN;
    float s = bias[f];
#pragma unroll 4
    for (int c = 0; c < CIN; ++c)
        s += xp[(size_t)c * (HFM * WFM)] * wp[c];
    feat[t] = s;
}

// ============ gather -> pf16 [M_][640] ============
__global__ __launch_bounds__(256) void gather_pf_k(const float* __restrict__ feat,
    const int* __restrict__ cut_xs, const unsigned char* __restrict__ invalid,
    ushort_t* __restrict__ pf16)
{
    long long t = (long long)blockIdx.x * 256 + threadIdx.x;
    if (t >= (long long)M_ * D_) return;
    int d = (int)(t % D_);
    int r = (int)(t / D_);
    int n = r % NANCH;
    int b = r / NANCH;
    int f = d / HFM, h = d - f * HFM;
    int idx = n * HFM + h;
    float v = 0.f;
    if (!invalid[idx]) {
        int xs = cut_xs[idx];
        v = feat[((size_t)(b * CF + f) * HFM + h) * WFM + xs];
    }
    pf16[t] = f2bf(v);
}

// ============ gather -> pfT16 [B][640][2784] ============
__global__ __launch_bounds__(256) void gather_pfT_k(const float* __restrict__ feat,
    const int* __restrict__ cut_xs, const unsigned char* __restrict__ invalid,
    ushort_t* __restrict__ pfT16)
{
    long long t = (long long)blockIdx.x * 256 + threadIdx.x;
    if (t >= (long long)B_ * D_ * NANCH) return;
    int n = (int)(t % NANCH);
    int d = (int)((t / NANCH) % D_);
    int b = (int)(t / ((long long)D_ * NANCH));
    int f = d / HFM, h = d - f * HFM;
    int idx = n * HFM + h;
    float v = 0.f;
    if (!invalid[idx]) {
        int xs = cut_xs[idx];
        v = feat[((size_t)(b * CF + f) * HFM + h) * WFM + xs];
    }
    pfT16[t] = f2bf(v);
}

// ============ attn_w fp32 [2783][640] -> bf16 padded [2816][640] ============
__global__ __launch_bounds__(256) void prep_attn_w_k(const float* __restrict__ attn_w,
    ushort_t* __restrict__ w16)
{
    int t = blockIdx.x * 256 + threadIdx.x;
    if (t >= NMPAD * D_) return;
    int m = t / D_;
    w16[t] = (m < NM) ? f2bf(attn_w[(size_t)m * D_ + (t % D_)]) : (ushort_t)0;
}

// ============ heads weights -> bf16 padded [128][1280] ============
__global__ __launch_bounds__(256) void prep_heads_w_k(const float* __restrict__ cls_w,
    const float* __restrict__ reg_w, ushort_t* __restrict__ w16)
{
    int t = blockIdx.x * 256 + threadIdx.x;
    if (t >= 128 * D2) return;
    int o = t / D2, k = t % D2;
    float v = 0.f;
    if (o < 2)       v = cls_w[(size_t)o * D2 + k];
    else if (o < 75) v = reg_w[(size_t)(o - 2) * D2 + k];
    w16[t] = (o < 75) ? f2bf(v) : (ushort_t)0;
}

// --------------------------------------------------------------------------
// MFMA kernels share this structure (depth-3 counted-vmcnt pipeline):
//   LDS tile layout [q:4][row:128][e:8]  (conflict-free ds_read_b128:
//     16 lanes read byte q*2048 + row*16 -> 8 banks x 2 lanes = free)
//   staging: wave `wid` stages k-slot `wid` for rows lane / 64+lane
//     (pre-swizzled GLOBAL source, linear LDS dest = gload_lds-compatible)
//   loop: STAGE(t+3); vmcnt(12); s_barrier; ds_read+MFMA(t)
//     -> 12 loads (3 tiles) stay in flight across the barrier
//   5 buffers: write target (t+3)%5 never collides with laggard reads (t-1)%5
// --------------------------------------------------------------------------

// ============ scores MFMA: s16[r][m+(m>=n)] = bf16(pf·attn_w^T + attn_b) ============
__global__ __launch_bounds__(256) void scores_mfma_k(
    const ushort_t* __restrict__ A,   // pf16 [M_][640]
    const ushort_t* __restrict__ Bw,  // attnw16 [2816][640]
    const float* __restrict__ attn_b,
    ushort_t* __restrict__ s16)       // attn16 buffer [M_+32][2784], pre-softmax bf16
{
    __shared__ __align__(16) ushort_t As[5][4096];
    __shared__ __align__(16) ushort_t Bs[5][4096];
    const int t = threadIdx.x;
    const int wid = t >> 6, lane = t & 63;
    const int wrow = (wid & 1) * 64, wcol = (wid >> 1) * 64;
    const int row0 = blockIdx.x * 128, col0 = blockIdx.y * 128;
    const ushort_t* pA = A  + (size_t)(row0 + lane) * D_ + wid * 8;
    const ushort_t* pB = Bw + (size_t)(col0 + lane) * D_ + wid * 8;
    f32x4 acc[4][4];
#pragma unroll
    for (int i = 0; i < 4; ++i)
#pragma unroll
        for (int j = 0; j < 4; ++j) acc[i][j] = (f32x4){0.f, 0.f, 0.f, 0.f};
    const int cl = lane & 15, q = lane >> 4;
    const int qb = q * 1024;

    auto STAGE = [&](int buf, int k0) {
        ushort_t* la = &As[buf][wid * 1024];
        ushort_t* lb = &Bs[buf][wid * 1024];
        gload16(pA + k0, la);
        gload16(pA + 64 * D_ + k0, la + 512);
        gload16(pB + k0, lb);
        gload16(pB + 64 * D_ + k0, lb + 512);
    };
    auto COMPUTE = [&](int buf) {
        short8 af[4], bv[4];
#pragma unroll
        for (int i = 0; i < 4; ++i) af[i] = *(const short8*)&As[buf][qb + (wrow + cl + i * 16) * 8];
#pragma unroll
        for (int j = 0; j < 4; ++j) bv[j] = *(const short8*)&Bs[buf][qb + (wcol + cl + j * 16) * 8];
        __builtin_amdgcn_s_setprio(1);
#pragma unroll
        for (int i = 0; i < 4; ++i)
#pragma unroll
            for (int j = 0; j < 4; ++j)
                acc[i][j] = __builtin_amdgcn_mfma_f32_16x16x32_bf16(af[i], bv[j], acc[i][j], 0, 0, 0);
        __builtin_amdgcn_s_setprio(0);
    };

    const int NT = D_ / 32;                 // 20
    STAGE(0, 0); STAGE(1, 32); STAGE(2, 64);
    int b0 = 0, b3 = 3;
    for (int it = 0; it < NT - 3; ++it) {
        STAGE(b3, (it + 3) * 32);
        VMCNT(12); S_BARRIER();
        COMPUTE(b0);
        b0 = (b0 == 4) ? 0 : b0 + 1;
        b3 = (b3 == 4) ? 0 : b3 + 1;
    }
    VMCNT(8); S_BARRIER(); COMPUTE(b0); b0 = (b0 == 4) ? 0 : b0 + 1;
    VMCNT(4); S_BARRIER(); COMPUTE(b0); b0 = (b0 == 4) ? 0 : b0 + 1;
    VMCNT(0); S_BARRIER(); COMPUTE(b0);

#pragma unroll
    for (int i = 0; i < 4; ++i) {
#pragma unroll
        for (int e = 0; e < 4; ++e) {
            int r = row0 + wrow + i * 16 + q * 4 + e;
            int n = r % NANCH;
            ushort_t* orow = s16 + (size_t)r * NANCH;
#pragma unroll
            for (int j = 0; j < 4; ++j) {
                int m = col0 + wcol + j * 16 + cl;
                if (m < NM) orow[m + (m >= n)] = f2bf(acc[i][j][e] + attn_b[m]);
            }
        }
    }
}

// ============ softmax per row: reads bf16 scores in-place, writes fp32 attn + bf16 back ============
__global__ __launch_bounds__(256) void softmax_k(float* __restrict__ attn,
    ushort_t* __restrict__ attn16)
{
    const int r = blockIdx.x;
    const int n = r % NANCH;
    float* row = attn + (size_t)r * NANCH;
    ushort_t* row16 = attn16 + (size_t)r * NANCH;
    const int t = threadIdx.x;
    __shared__ float red[4];
    float vals[12];                           // static-indexed -> stays in VGPRs
    float mx = -1e30f;
#pragma unroll
    for (int i = 0; i < 6; ++i) {             // 1392 ushort2 per row
        int c = t + i * 256;
        float v0 = -1e30f, v1 = -1e30f;
        if (c < 1392) {
            uint32 u = *(const uint32*)&row16[2 * c];
            v0 = (2 * c     == n) ? -1e30f : bf2f((ushort_t)(u & 0xffffu));
            v1 = (2 * c + 1 == n) ? -1e30f : bf2f((ushort_t)(u >> 16));
        }
        vals[2 * i] = v0; vals[2 * i + 1] = v1;
        mx = fmaxf(mx, fmaxf(v0, v1));
    }
    for (int off = 32; off; off >>= 1) mx = fmaxf(mx, __shfl_down(mx, off));
    if ((t & 63) == 0) red[t >> 6] = mx;
    __syncthreads();
    mx = fmaxf(fmaxf(red[0], red[1]), fmaxf(red[2], red[3]));
    __syncthreads();
    float s = 0.f;
#pragma unroll
    for (int i = 0; i < 12; ++i) {
        float e = __expf(vals[i] - mx);       // diag/OOB: exp(-1e30-mx) = 0
        vals[i] = e;
        s += e;
    }
    for (int off = 32; off; off >>= 1) s += __shfl_down(s, off);
    if ((t & 63) == 0) red[t >> 6] = s;
    __syncthreads();
    s = red[0] + red[1] + red[2] + red[3];
    float inv = 1.0f / s;
#pragma unroll
    for (int i = 0; i < 6; ++i) {
        int c = t + i * 256;
        if (c < 1392) {
            float v0 = vals[2 * i] * inv, v1 = vals[2 * i + 1] * inv;
            *(float2*)&row[2 * c] = make_float2(v0, v1);
            uint32 pk = (uint32)f2bf(v0) | ((uint32)f2bf(v1) << 16);
            *(uint32*)&row16[2 * c] = pk;
        }
    }
}

// ============ att MFMA: att16[b][n][d] = attn16[b][n][:]·pfT[b][d][:] ============
__global__ __launch_bounds__(256) void att_mfma_k(
    const ushort_t* __restrict__ A16,  // attn16 [M_+32][2784]
    const ushort_t* __restrict__ Bt,   // pfT16 [B][640][2784]
    ushort_t* __restrict__ att16)      // [B][2784][640]
{
    __shared__ __align__(16) ushort_t As[5][4096];
    __shared__ __align__(16) ushort_t Bs[5][4096];
    // XCD-aware decode (grid=880, bid%8=XCD): each XCD owns one batch
    // (pfT[b]=3.56MB L2-resident); cols innermost -> A-slab read once per L2.
    const int bid = blockIdx.x;
    const int u = bid >> 3;
    const int colb = u % 5;
    const int pair = u / 5;            // row-slab 0..21
    const int b = bid & 7;             // batch == xcd
    const int row0 = pair * 128, col0 = colb * 128;
    const int t = threadIdx.x;
    const int wid = t >> 6, lane = t & 63;
    const int wrow = (wid & 1) * 64, wcol = (wid >> 1) * 64;
    // A rows may over-read past batch end (padded +32 rows at buffer end); results discarded.
    const ushort_t* pA = A16 + ((size_t)b * NANCH + row0 + lane) * NANCH + wid * 8;
    const ushort_t* pB = Bt  + ((size_t)b * D_ + col0 + lane) * NANCH + wid * 8;
    f32x4 acc[4][4];
#pragma unroll
    for (int i = 0; i < 4; ++i)
#pragma unroll
        for (int j = 0; j < 4; ++j) acc[i][j] = (f32x4){0.f, 0.f, 0.f, 0.f};
    const int cl = lane & 15, q = lane >> 4;
    const int qb = q * 1024;

    auto STAGE = [&](int buf, int k0) {
        ushort_t* la = &As[buf][wid * 1024];
        ushort_t* lb = &Bs[buf][wid * 1024];
        gload16(pA + k0, la);
        gload16(pA + (size_t)64 * NANCH + k0, la + 512);
        gload16(pB + k0, lb);
        gload16(pB + (size_t)64 * NANCH + k0, lb + 512);
    };
    auto COMPUTE = [&](int buf) {
        short8 af[4], bv[4];
#pragma unroll
        for (int i = 0; i < 4; ++i) af[i] = *(const short8*)&As[buf][qb + (wrow + cl + i * 16) * 8];
#pragma unroll
        for (int j = 0; j < 4; ++j) bv[j] = *(const short8*)&Bs[buf][qb + (wcol + cl + j * 16) * 8];
        __builtin_amdgcn_s_setprio(1);
#pragma unroll
        for (int i = 0; i < 4; ++i)
#pragma unroll
            for (int j = 0; j < 4; ++j)
                acc[i][j] = __builtin_amdgcn_mfma_f32_16x16x32_bf16(af[i], bv[j], acc[i][j], 0, 0, 0);
        __builtin_amdgcn_s_setprio(0);
    };

    const int NT = NANCH / 32;              // 87
    STAGE(0, 0); STAGE(1, 32); STAGE(2, 64);
    int b0 = 0, b3 = 3;
    for (int it = 0; it < NT - 3; ++it) {
        STAGE(b3, (it + 3) * 32);
        VMCNT(12); S_BARRIER();
        COMPUTE(b0);
        b0 = (b0 == 4) ? 0 : b0 + 1;
        b3 = (b3 == 4) ? 0 : b3 + 1;
    }
    VMCNT(8); S_BARRIER(); COMPUTE(b0); b0 = (b0 == 4) ? 0 : b0 + 1;
    VMCNT(4); S_BARRIER(); COMPUTE(b0); b0 = (b0 == 4) ? 0 : b0 + 1;
    VMCNT(0); S_BARRIER(); COMPUTE(b0);

#pragma unroll
    for (int i = 0; i < 4; ++i) {
#pragma unroll
        for (int e = 0; e < 4; ++e) {
            int row = row0 + wrow + i * 16 + q * 4 + e;
            if (row < NANCH) {
                ushort_t* orow = att16 + ((size_t)b * NANCH + row) * D_;
#pragma unroll
                for (int j = 0; j < 4; ++j) {
                    int d = col0 + wcol + j * 16 + cl;
                    orow[d] = f2bf(acc[i][j][e]);
                }
            }
        }
    }
}

// ============ heads MFMA: [cls|reg] = [att16|pf16]·W^T; fused lanes epilogue ============
__global__ __launch_bounds__(256) void heads_mfma_k(
    const ushort_t* __restrict__ att16, const ushort_t* __restrict__ pf16,
    const ushort_t* __restrict__ W,    // [128][1280] bf16 padded
    const float* __restrict__ cls_b, const float* __restrict__ reg_b,
    const float* __restrict__ anchors,
    float* __restrict__ cls_out, float* __restrict__ lanes)
{
    __shared__ __align__(16) ushort_t As[5][4096];
    __shared__ __align__(16) ushort_t Bs[5][4096];
    const int t = threadIdx.x;
    const int wid = t >> 6, lane = t & 63;
    const int wrow = (wid & 1) * 64, wcol = (wid >> 1) * 64;
    const int row0 = blockIdx.x * 128;
    const ushort_t* pAa = att16 + (size_t)(row0 + lane) * D_ + wid * 8;
    const ushort_t* pAp = pf16  + (size_t)(row0 + lane) * D_ + wid * 8;
    const ushort_t* pB  = W + (size_t)lane * D2 + wid * 8;
    f32x4 acc[4][4];
#pragma unroll
    for (int i = 0; i < 4; ++i)
#pragma unroll
        for (int j = 0; j < 4; ++j) acc[i][j] = (f32x4){0.f, 0.f, 0.f, 0.f};
    const int cl = lane & 15, q = lane >> 4;
    const int qb = q * 1024;

    auto STAGE = [&](int buf, int k0) {
        const ushort_t* ga = (k0 < D_) ? pAa + k0 : pAp + (k0 - D_);
        ushort_t* la = &As[buf][wid * 1024];
        ushort_t* lb = &Bs[buf][wid * 1024];
        gload16(ga, la);
        gload16(ga + 64 * D_, la + 512);
        gload16(pB + k0, lb);
        gload16(pB + 64 * D2 + k0, lb + 512);
    };
    auto COMPUTE = [&](int buf) {
        short8 af[4], bv[4];
#pragma unroll
        for (int i = 0; i < 4; ++i) af[i] = *(const short8*)&As[buf][qb + (wrow + cl + i * 16) * 8];
#pragma unroll
        for (int j = 0; j < 4; ++j) bv[j] = *(const short8*)&Bs[buf][qb + (wcol + cl + j * 16) * 8];
        __builtin_amdgcn_s_setprio(1);
#pragma unroll
        for (int i = 0; i < 4; ++i)
#pragma unroll
            for (int j = 0; j < 4; ++j)
                acc[i][j] = __builtin_amdgcn_mfma_f32_16x16x32_bf16(af[i], bv[j], acc[i][j], 0, 0, 0);
        __builtin_amdgcn_s_setprio(0);
    };

    const int NT = D2 / 32;                 // 40
    STAGE(0, 0); STAGE(1, 32); STAGE(2, 64);
    int b0 = 0, b3 = 3;
    for (int it = 0; it < NT - 3; ++it) {
        STAGE(b3, (it + 3) * 32);
        VMCNT(12); S_BARRIER();
        COMPUTE(b0);
        b0 = (b0 == 4) ? 0 : b0 + 1;
        b3 = (b3 == 4) ? 0 : b3 + 1;
    }
    VMCNT(8); S_BARRIER(); COMPUTE(b0); b0 = (b0 == 4) ? 0 : b0 + 1;
    VMCNT(4); S_BARRIER(); COMPUTE(b0); b0 = (b0 == 4) ? 0 : b0 + 1;
    VMCNT(0); S_BARRIER(); COMPUTE(b0);

#pragma unroll
    for (int i = 0; i < 4; ++i) {
#pragma unroll
        for (int e = 0; e < 4; ++e) {
            int r = row0 + wrow + i * 16 + q * 4 + e;
            int n = r % NANCH;
#pragma unroll
            for (int j = 0; j < 4; ++j) {
                int oo = wcol + j * 16 + cl;
                float v = acc[i][j][e];
                if (oo < 2) {
                    cls_out[(size_t)r * 2 + oo] = v + cls_b[oo];
                } else if (oo < 75) {
                    int qq = oo - 2;
                    int c = 4 + qq;
                    float res = v + reg_b[qq];
                    if (qq > 0) res += anchors[(size_t)n * ALEN + c];
                    lanes[(size_t)r * ALEN + c] = res;
                } else if (oo < 79) {
                    int c = oo - 75;                      // lanes cols 0..3 = anchors
                    lanes[(size_t)r * ALEN + c] = anchors[(size_t)n * ALEN + c];
                }
            }
        }
    }
}

extern "C" void kernel_launch(void* const* d_in, const int* in_sizes, int n_in,
                              void* d_out, int out_size, void* d_ws, size_t ws_size,
                              hipStream_t stream)
{
    (void)in_sizes; (void)n_in; (void)out_size; (void)ws_size;
    const float* x       = (const float*)d_in[0];
    const float* conv_w  = (const float*)d_in[1];
    const float* conv_b  = (const float*)d_in[2];
    const float* attn_w  = (const float*)d_in[3];
    const float* attn_b  = (const float*)d_in[4];
    const float* cls_w   = (const float*)d_in[5];
    const float* cls_b   = (const float*)d_in[6];
    const float* reg_w   = (const float*)d_in[7];
    const float* reg_b   = (const float*)d_in[8];
    const float* anchors = (const float*)d_in[9];
    const int*   cut_xs  = (const int*)d_in[10];
    const unsigned char* invalid = (const unsigned char*)d_in[11];

    float* out     = (float*)d_out;
    float* cls_out = out;
    float* lanes   = out + (size_t)M_ * 2;
    float* attn    = out + (size_t)M_ * 2 + (size_t)M_ * ALEN;

    // workspace layout (~215 MB)
    char* w = (char*)d_ws;
    float* feat      = (float*)w;    w += (size_t)B_ * CF * HFM * WFM * 4;       // 512 KB
    ushort_t* pf16   = (ushort_t*)w; w += (size_t)M_ * D_ * 2;                   // 28.5 MB
    ushort_t* pfT16  = (ushort_t*)w; w += (size_t)B_ * D_ * NANCH * 2;           // 28.5 MB
    ushort_t* aw16   = (ushort_t*)w; w += (size_t)NMPAD * D_ * 2;                // 3.6 MB
    ushort_t* att16  = (ushort_t*)w; w += (size_t)M_ * D_ * 2;                   // 28.5 MB
    ushort_t* hw16   = (ushort_t*)w; w += (size_t)128 * D2 * 2;                  // 320 KB
    ushort_t* attn16 = (ushort_t*)w; w += (size_t)(M_ + 32) * NANCH * 2;         // 124.2 MB (+32-row pad)

    conv_feat_k<<<(B_ * CF * HFM * WFM + 255) / 256, 256, 0, stream>>>(x, conv_w, conv_b, feat);
    gather_pf_k<<<(int)(((long long)M_ * D_ + 255) / 256), 256, 0, stream>>>(feat, cut_xs, invalid, pf16);
    gather_pfT_k<<<(int)(((long long)B_ * D_ * NANCH + 255) / 256), 256, 0, stream>>>(feat, cut_xs, invalid, pfT16);
    prep_attn_w_k<<<(NMPAD * D_ + 255) / 256, 256, 0, stream>>>(attn_w, aw16);
    prep_heads_w_k<<<(128 * D2 + 255) / 256, 256, 0, stream>>>(cls_w, reg_w, hw16);

    scores_mfma_k<<<dim3(M_ / 128, NMPAD / 128), 256, 0, stream>>>(pf16, aw16, attn_b, attn16);
    softmax_k<<<M_, 256, 0, stream>>>(attn, attn16);
    att_mfma_k<<<dim3(22 * 5 * B_), 256, 0, stream>>>(attn16, pfT16, att16);
    heads_mfma_k<<<dim3(M_ / 128), 256, 0, stream>>>(att16, pf16, hw16, cls_b, reg_b, anchors, cls_out, lanes);
}

// Round 3
// 649.017 us; speedup vs baseline: 1.2531x; 1.2531x over previous
//
#include <hip/hip_runtime.h>

typedef unsigned short ushort_t;
typedef unsigned int   uint32;
typedef __attribute__((ext_vector_type(8))) short short8;   // 8 bf16 (4 VGPRs)
typedef __attribute__((ext_vector_type(4))) float f32x4;    // MFMA acc

// ---------------- problem constants ----------------
#define B_     8
#define CIN    512
#define HFM    10
#define WFM    25
#define CF     64
#define NANCH  2784          // N
#define NM     2783          // N-1
#define NMPAD  2816          // N-1 padded to 128
#define D_     640           // CF*HFM
#define D2     1280
#define ALEN   77
#define M_     (B_*NANCH)    // 22272

// counted-vmcnt pipeline helpers (T4): never drain vmcnt to 0 in the main loop
#define VMCNT(N)   asm volatile("s_waitcnt vmcnt(" #N ")" ::: "memory")
#define S_BARRIER() do { __builtin_amdgcn_s_barrier(); __builtin_amdgcn_sched_barrier(0); } while (0)

__device__ __forceinline__ ushort_t f2bf(float f) {
    uint32 u = __float_as_uint(f);
    u += 0x7fffu + ((u >> 16) & 1u);     // RNE
    return (ushort_t)(u >> 16);
}
__device__ __forceinline__ float bf2f(ushort_t h) {
    return __uint_as_float(((uint32)h) << 16);
}

__device__ __forceinline__ void gload16(const ushort_t* g, ushort_t* l) {
    __builtin_amdgcn_global_load_lds(
        (const __attribute__((address_space(1))) void*)g,
        (__attribute__((address_space(3))) void*)l, 16, 0, 0);
}

// ============ 1x1 conv ============
__global__ __launch_bounds__(256) void conv_feat_k(const float* __restrict__ x,
    const float* __restrict__ w, const float* __restrict__ bias,
    float* __restrict__ feat)
{
    int t = blockIdx.x * 256 + threadIdx.x;
    if (t >= B_ * CF * HFM * WFM) return;
    int pos = t % (HFM * WFM);
    int f   = (t / (HFM * WFM)) % CF;
    int b   = t / (CF * HFM * WFM);
    const float* xp = x + (size_t)b * CIN * HFM * WFM + pos;
    const float* wp = w + (size_t)f * CIN;
    float s = bias[f];
#pragma unroll 4
    for (int c = 0; c < CIN; ++c)
        s += xp[(size_t)c * (HFM * WFM)] * wp[c];
    feat[t] = s;
}

// ============ gather -> pf16 [M_][640] ============
__global__ __launch_bounds__(256) void gather_pf_k(const float* __restrict__ feat,
    const int* __restrict__ cut_xs, const unsigned char* __restrict__ invalid,
    ushort_t* __restrict__ pf16)
{
    long long t = (long long)blockIdx.x * 256 + threadIdx.x;
    if (t >= (long long)M_ * D_) return;
    int d = (int)(t % D_);
    int r = (int)(t / D_);
    int n = r % NANCH;
    int b = r / NANCH;
    int f = d / HFM, h = d - f * HFM;
    int idx = n * HFM + h;
    float v = 0.f;
    if (!invalid[idx]) {
        int xs = cut_xs[idx];
        v = feat[((size_t)(b * CF + f) * HFM + h) * WFM + xs];
    }
    pf16[t] = f2bf(v);
}

// ============ gather -> pfT16 [B][640][2784] ============
__global__ __launch_bounds__(256) void gather_pfT_k(const float* __restrict__ feat,
    const int* __restrict__ cut_xs, const unsigned char* __restrict__ invalid,
    ushort_t* __restrict__ pfT16)
{
    long long t = (long long)blockIdx.x * 256 + threadIdx.x;
    if (t >= (long long)B_ * D_ * NANCH) return;
    int n = (int)(t % NANCH);
    int d = (int)((t / NANCH) % D_);
    int b = (int)(t / ((long long)D_ * NANCH));
    int f = d / HFM, h = d - f * HFM;
    int idx = n * HFM + h;
    float v = 0.f;
    if (!invalid[idx]) {
        int xs = cut_xs[idx];
        v = feat[((size_t)(b * CF + f) * HFM + h) * WFM + xs];
    }
    pfT16[t] = f2bf(v);
}

// ============ attn_w fp32 [2783][640] -> bf16 padded [2816][640] ============
__global__ __launch_bounds__(256) void prep_attn_w_k(const float* __restrict__ attn_w,
    ushort_t* __restrict__ w16)
{
    int t = blockIdx.x * 256 + threadIdx.x;
    if (t >= NMPAD * D_) return;
    int m = t / D_;
    w16[t] = (m < NM) ? f2bf(attn_w[(size_t)m * D_ + (t % D_)]) : (ushort_t)0;
}

// ============ heads weights -> bf16 padded [128][1280] ============
__global__ __launch_bounds__(256) void prep_heads_w_k(const float* __restrict__ cls_w,
    const float* __restrict__ reg_w, ushort_t* __restrict__ w16)
{
    int t = blockIdx.x * 256 + threadIdx.x;
    if (t >= 128 * D2) return;
    int o = t / D2, k = t % D2;
    float v = 0.f;
    if (o < 2)       v = cls_w[(size_t)o * D2 + k];
    else if (o < 75) v = reg_w[(size_t)(o - 2) * D2 + k];
    w16[t] = (o < 75) ? f2bf(v) : (ushort_t)0;
}

// --------------------------------------------------------------------------
// MFMA kernels: depth-3 counted-vmcnt pipeline + chunk-XOR LDS swizzle.
//   LDS tile: row-major [row:128][32 elems] (64B rows), with the four 16B
//   chunks of each row permuted: slot s of row R holds global chunk
//   s ^ ((R>>1)&3).  (Same involution on staging source and ds_read.)
//   Staging (wave wid, lane l): row = wid*16 + l/4 (+64 for 2nd load),
//     global chunk = (l&3) ^ ((l>>3)&3)  -> per-4-lane group covers a FULL
//     64B line (coalesced, 16 lines/instr), LDS dest stays linear.
//   Read: fragment (row R, chunk q) at R*32 + (q^((R>>1)&3))*8 ->
//     16 lanes spread over 8 distinct 4-bank groups, 2 lanes each = free.
//   Loop: STAGE(t+3); vmcnt(12); s_barrier; ds_read+MFMA(t).
//   5 buffers: write target (t+3)%5 never collides with laggard reads (t-1)%5.
// --------------------------------------------------------------------------

// ============ scores MFMA: s16[r][m+(m>=n)] = bf16(pf·attn_w^T + attn_b) ============
__global__ __launch_bounds__(256) void scores_mfma_k(
    const ushort_t* __restrict__ A,   // pf16 [M_][640]
    const ushort_t* __restrict__ Bw,  // attnw16 [2816][640]
    const float* __restrict__ attn_b,
    ushort_t* __restrict__ s16)       // attn16 buffer [M_+32][2784], pre-softmax bf16
{
    __shared__ __align__(16) ushort_t As[5][4096];
    __shared__ __align__(16) ushort_t Bs[5][4096];
    const int t = threadIdx.x;
    const int wid = t >> 6, lane = t & 63;
    const int wrow = (wid & 1) * 64, wcol = (wid >> 1) * 64;
    const int row0 = blockIdx.x * 128, col0 = blockIdx.y * 128;
    const int swrow = wid * 16 + (lane >> 2);                       // staged row
    const int swk   = (((lane & 3) ^ ((lane >> 3) & 3)) * 8);       // swizzled chunk
    const ushort_t* pA = A  + (size_t)(row0 + swrow) * D_ + swk;
    const ushort_t* pB = Bw + (size_t)(col0 + swrow) * D_ + swk;
    f32x4 acc[4][4];
#pragma unroll
    for (int i = 0; i < 4; ++i)
#pragma unroll
        for (int j = 0; j < 4; ++j) acc[i][j] = (f32x4){0.f, 0.f, 0.f, 0.f};
    const int cl = lane & 15, q = lane >> 4;
    const int ra = wrow + cl, rb = wcol + cl;
    const int aoff = ra * 32 + ((q ^ ((ra >> 1) & 3)) * 8);
    const int boff = rb * 32 + ((q ^ ((rb >> 1) & 3)) * 8);

    auto STAGE = [&](int buf, int k0) {
        ushort_t* la = &As[buf][wid * 512];
        ushort_t* lb = &Bs[buf][wid * 512];
        gload16(pA + k0, la);
        gload16(pA + 64 * D_ + k0, la + 2048);
        gload16(pB + k0, lb);
        gload16(pB + 64 * D_ + k0, lb + 2048);
    };
    auto COMPUTE = [&](int buf) {
        short8 af[4], bv[4];
#pragma unroll
        for (int i = 0; i < 4; ++i) af[i] = *(const short8*)&As[buf][aoff + i * 512];
#pragma unroll
        for (int j = 0; j < 4; ++j) bv[j] = *(const short8*)&Bs[buf][boff + j * 512];
        __builtin_amdgcn_s_setprio(1);
#pragma unroll
        for (int i = 0; i < 4; ++i)
#pragma unroll
            for (int j = 0; j < 4; ++j)
                acc[i][j] = __builtin_amdgcn_mfma_f32_16x16x32_bf16(af[i], bv[j], acc[i][j], 0, 0, 0);
        __builtin_amdgcn_s_setprio(0);
    };

    const int NT = D_ / 32;                 // 20
    STAGE(0, 0); STAGE(1, 32); STAGE(2, 64);
    int b0 = 0, b3 = 3;
    for (int it = 0; it < NT - 3; ++it) {
        STAGE(b3, (it + 3) * 32);
        VMCNT(12); S_BARRIER();
        COMPUTE(b0);
        b0 = (b0 == 4) ? 0 : b0 + 1;
        b3 = (b3 == 4) ? 0 : b3 + 1;
    }
    VMCNT(8); S_BARRIER(); COMPUTE(b0); b0 = (b0 == 4) ? 0 : b0 + 1;
    VMCNT(4); S_BARRIER(); COMPUTE(b0); b0 = (b0 == 4) ? 0 : b0 + 1;
    VMCNT(0); S_BARRIER(); COMPUTE(b0);

#pragma unroll
    for (int i = 0; i < 4; ++i) {
#pragma unroll
        for (int e = 0; e < 4; ++e) {
            int r = row0 + wrow + i * 16 + q * 4 + e;
            int n = r % NANCH;
            ushort_t* orow = s16 + (size_t)r * NANCH;
#pragma unroll
            for (int j = 0; j < 4; ++j) {
                int m = col0 + wcol + j * 16 + cl;
                if (m < NM) orow[m + (m >= n)] = f2bf(acc[i][j][e] + attn_b[m]);
            }
        }
    }
}

// ============ softmax per row: reads bf16 scores in-place, writes fp32 attn + bf16 back ============
__global__ __launch_bounds__(256) void softmax_k(float* __restrict__ attn,
    ushort_t* __restrict__ attn16)
{
    const int r = blockIdx.x;
    const int n = r % NANCH;
    float* row = attn + (size_t)r * NANCH;
    ushort_t* row16 = attn16 + (size_t)r * NANCH;
    const int t = threadIdx.x;
    __shared__ float red[4];
    float vals[12];                           // static-indexed -> stays in VGPRs
    float mx = -1e30f;
#pragma unroll
    for (int i = 0; i < 6; ++i) {             // 1392 ushort2 per row
        int c = t + i * 256;
        float v0 = -1e30f, v1 = -1e30f;
        if (c < 1392) {
            uint32 u = *(const uint32*)&row16[2 * c];
            v0 = (2 * c     == n) ? -1e30f : bf2f((ushort_t)(u & 0xffffu));
            v1 = (2 * c + 1 == n) ? -1e30f : bf2f((ushort_t)(u >> 16));
        }
        vals[2 * i] = v0; vals[2 * i + 1] = v1;
        mx = fmaxf(mx, fmaxf(v0, v1));
    }
    for (int off = 32; off; off >>= 1) mx = fmaxf(mx, __shfl_down(mx, off));
    if ((t & 63) == 0) red[t >> 6] = mx;
    __syncthreads();
    mx = fmaxf(fmaxf(red[0], red[1]), fmaxf(red[2], red[3]));
    __syncthreads();
    float s = 0.f;
#pragma unroll
    for (int i = 0; i < 12; ++i) {
        float e = __expf(vals[i] - mx);       // diag/OOB: exp(-1e30-mx) = 0
        vals[i] = e;
        s += e;
    }
    for (int off = 32; off; off >>= 1) s += __shfl_down(s, off);
    if ((t & 63) == 0) red[t >> 6] = s;
    __syncthreads();
    s = red[0] + red[1] + red[2] + red[3];
    float inv = 1.0f / s;
#pragma unroll
    for (int i = 0; i < 6; ++i) {
        int c = t + i * 256;
        if (c < 1392) {
            float v0 = vals[2 * i] * inv, v1 = vals[2 * i + 1] * inv;
            *(float2*)&row[2 * c] = make_float2(v0, v1);
            uint32 pk = (uint32)f2bf(v0) | ((uint32)f2bf(v1) << 16);
            *(uint32*)&row16[2 * c] = pk;
        }
    }
}

// ============ att MFMA: att16[b][n][d] = attn16[b][n][:]·pfT[b][d][:] ============
__global__ __launch_bounds__(256) void att_mfma_k(
    const ushort_t* __restrict__ A16,  // attn16 [M_+32][2784]
    const ushort_t* __restrict__ Bt,   // pfT16 [B][640][2784]
    ushort_t* __restrict__ att16)      // [B][2784][640]
{
    __shared__ __align__(16) ushort_t As[5][4096];
    __shared__ __align__(16) ushort_t Bs[5][4096];
    // XCD-aware decode (grid=880, bid%8=XCD): each XCD owns one batch
    // (pfT[b]=3.56MB L2-resident); cols innermost -> A-slab read once per L2.
    const int bid = blockIdx.x;
    const int u = bid >> 3;
    const int colb = u % 5;
    const int pair = u / 5;            // row-slab 0..21
    const int b = bid & 7;             // batch == xcd
    const int row0 = pair * 128, col0 = colb * 128;
    const int t = threadIdx.x;
    const int wid = t >> 6, lane = t & 63;
    const int wrow = (wid & 1) * 64, wcol = (wid >> 1) * 64;
    const int swrow = wid * 16 + (lane >> 2);
    const int swk   = (((lane & 3) ^ ((lane >> 3) & 3)) * 8);
    // A rows may over-read past batch end (padded +32 rows at buffer end); results discarded.
    const ushort_t* pA = A16 + ((size_t)b * NANCH + row0 + swrow) * NANCH + swk;
    const ushort_t* pB = Bt  + ((size_t)b * D_ + col0 + swrow) * NANCH + swk;
    f32x4 acc[4][4];
#pragma unroll
    for (int i = 0; i < 4; ++i)
#pragma unroll
        for (int j = 0; j < 4; ++j) acc[i][j] = (f32x4){0.f, 0.f, 0.f, 0.f};
    const int cl = lane & 15, q = lane >> 4;
    const int ra = wrow + cl, rb = wcol + cl;
    const int aoff = ra * 32 + ((q ^ ((ra >> 1) & 3)) * 8);
    const int boff = rb * 32 + ((q ^ ((rb >> 1) & 3)) * 8);

    auto STAGE = [&](int buf, int k0) {
        ushort_t* la = &As[buf][wid * 512];
        ushort_t* lb = &Bs[buf][wid * 512];
        gload16(pA + k0, la);
        gload16(pA + (size_t)64 * NANCH + k0, la + 2048);
        gload16(pB + k0, lb);
        gload16(pB + (size_t)64 * NANCH + k0, lb + 2048);
    };
    auto COMPUTE = [&](int buf) {
        short8 af[4], bv[4];
#pragma unroll
        for (int i = 0; i < 4; ++i) af[i] = *(const short8*)&As[buf][aoff + i * 512];
#pragma unroll
        for (int j = 0; j < 4; ++j) bv[j] = *(const short8*)&Bs[buf][boff + j * 512];
        __builtin_amdgcn_s_setprio(1);
#pragma unroll
        for (int i = 0; i < 4; ++i)
#pragma unroll
            for (int j = 0; j < 4; ++j)
                acc[i][j] = __builtin_amdgcn_mfma_f32_16x16x32_bf16(af[i], bv[j], acc[i][j], 0, 0, 0);
        __builtin_amdgcn_s_setprio(0);
    };

    const int NT = NANCH / 32;              // 87
    STAGE(0, 0); STAGE(1, 32); STAGE(2, 64);
    int b0 = 0, b3 = 3;
    for (int it = 0; it < NT - 3; ++it) {
        STAGE(b3, (it + 3) * 32);
        VMCNT(12); S_BARRIER();
        COMPUTE(b0);
        b0 = (b0 == 4) ? 0 : b0 + 1;
        b3 = (b3 == 4) ? 0 : b3 + 1;
    }
    VMCNT(8); S_BARRIER(); COMPUTE(b0); b0 = (b0 == 4) ? 0 : b0 + 1;
    VMCNT(4); S_BARRIER(); COMPUTE(b0); b0 = (b0 == 4) ? 0 : b0 + 1;
    VMCNT(0); S_BARRIER(); COMPUTE(b0);

#pragma unroll
    for (int i = 0; i < 4; ++i) {
#pragma unroll
        for (int e = 0; e < 4; ++e) {
            int row = row0 + wrow + i * 16 + q * 4 + e;
            if (row < NANCH) {
                ushort_t* orow = att16 + ((size_t)b * NANCH + row) * D_;
#pragma unroll
                for (int j = 0; j < 4; ++j) {
                    int d = col0 + wcol + j * 16 + cl;
                    orow[d] = f2bf(acc[i][j][e]);
                }
            }
        }
    }
}

// ============ heads MFMA: [cls|reg] = [att16|pf16]·W^T; fused lanes epilogue ============
__global__ __launch_bounds__(256) void heads_mfma_k(
    const ushort_t* __restrict__ att16, const ushort_t* __restrict__ pf16,
    const ushort_t* __restrict__ W,    // [128][1280] bf16 padded
    const float* __restrict__ cls_b, const float* __restrict__ reg_b,
    const float* __restrict__ anchors,
    float* __restrict__ cls_out, float* __restrict__ lanes)
{
    __shared__ __align__(16) ushort_t As[5][4096];
    __shared__ __align__(16) ushort_t Bs[5][4096];
    const int t = threadIdx.x;
    const int wid = t >> 6, lane = t & 63;
    const int wrow = (wid & 1) * 64, wcol = (wid >> 1) * 64;
    const int row0 = blockIdx.x * 128;
    const int swrow = wid * 16 + (lane >> 2);
    const int swk   = (((lane & 3) ^ ((lane >> 3) & 3)) * 8);
    const ushort_t* pAa = att16 + (size_t)(row0 + swrow) * D_ + swk;
    const ushort_t* pAp = pf16  + (size_t)(row0 + swrow) * D_ + swk;
    const ushort_t* pB  = W + (size_t)swrow * D2 + swk;
    f32x4 acc[4][4];
#pragma unroll
    for (int i = 0; i < 4; ++i)
#pragma unroll
        for (int j = 0; j < 4; ++j) acc[i][j] = (f32x4){0.f, 0.f, 0.f, 0.f};
    const int cl = lane & 15, q = lane >> 4;
    const int ra = wrow + cl, rb = wcol + cl;
    const int aoff = ra * 32 + ((q ^ ((ra >> 1) & 3)) * 8);
    const int boff = rb * 32 + ((q ^ ((rb >> 1) & 3)) * 8);

    auto STAGE = [&](int buf, int k0) {
        const ushort_t* ga = (k0 < D_) ? pAa + k0 : pAp + (k0 - D_);
        ushort_t* la = &As[buf][wid * 512];
        ushort_t* lb = &Bs[buf][wid * 512];
        gload16(ga, la);
        gload16(ga + 64 * D_, la + 2048);
        gload16(pB + k0, lb);
        gload16(pB + 64 * D2 + k0, lb + 2048);
    };
    auto COMPUTE = [&](int buf) {
        short8 af[4], bv[4];
#pragma unroll
        for (int i = 0; i < 4; ++i) af[i] = *(const short8*)&As[buf][aoff + i * 512];
#pragma unroll
        for (int j = 0; j < 4; ++j) bv[j] = *(const short8*)&Bs[buf][boff + j * 512];
        __builtin_amdgcn_s_setprio(1);
#pragma unroll
        for (int i = 0; i < 4; ++i)
#pragma unroll
            for (int j = 0; j < 4; ++j)
                acc[i][j] = __builtin_amdgcn_mfma_f32_16x16x32_bf16(af[i], bv[j], acc[i][j], 0, 0, 0);
        __builtin_amdgcn_s_setprio(0);
    };

    const int NT = D2 / 32;                 // 40
    STAGE(0, 0); STAGE(1, 32); STAGE(2, 64);
    int b0 = 0, b3 = 3;
    for (int it = 0; it < NT - 3; ++it) {
        STAGE(b3, (it + 3) * 32);
        VMCNT(12); S_BARRIER();
        COMPUTE(b0);
        b0 = (b0 == 4) ? 0 : b0 + 1;
        b3 = (b3 == 4) ? 0 : b3 + 1;
    }
    VMCNT(8); S_BARRIER(); COMPUTE(b0); b0 = (b0 == 4) ? 0 : b0 + 1;
    VMCNT(4); S_BARRIER(); COMPUTE(b0); b0 = (b0 == 4) ? 0 : b0 + 1;
    VMCNT(0); S_BARRIER(); COMPUTE(b0);

#pragma unroll
    for (int i = 0; i < 4; ++i) {
#pragma unroll
        for (int e = 0; e < 4; ++e) {
            int r = row0 + wrow + i * 16 + q * 4 + e;
            int n = r % NANCH;
#pragma unroll
            for (int j = 0; j < 4; ++j) {
                int oo = wcol + j * 16 + cl;
                float v = acc[i][j][e];
                if (oo < 2) {
                    cls_out[(size_t)r * 2 + oo] = v + cls_b[oo];
                } else if (oo < 75) {
                    int qq = oo - 2;
                    int c = 4 + qq;
                    float res = v + reg_b[qq];
                    if (qq > 0) res += anchors[(size_t)n * ALEN + c];
                    lanes[(size_t)r * ALEN + c] = res;
                } else if (oo < 79) {
                    int c = oo - 75;                      // lanes cols 0..3 = anchors
                    lanes[(size_t)r * ALEN + c] = anchors[(size_t)n * ALEN + c];
                }
            }
        }
    }
}

extern "C" void kernel_launch(void* const* d_in, const int* in_sizes, int n_in,
                              void* d_out, int out_size, void* d_ws, size_t ws_size,
                              hipStream_t stream)
{
    (void)in_sizes; (void)n_in; (void)out_size; (void)ws_size;
    const float* x       = (const float*)d_in[0];
    const float* conv_w  = (const float*)d_in[1];
    const float* conv_b  = (const float*)d_in[2];
    const float* attn_w  = (const float*)d_in[3];
    const float* attn_b  = (const float*)d_in[4];
    const float* cls_w   = (const float*)d_in[5];
    const float* cls_b   = (const float*)d_in[6];
    const float* reg_w   = (const float*)d_in[7];
    const float* reg_b   = (const float*)d_in[8];
    const float* anchors = (const float*)d_in[9];
    const int*   cut_xs  = (const int*)d_in[10];
    const unsigned char* invalid = (const unsigned char*)d_in[11];

    float* out     = (float*)d_out;
    float* cls_out = out;
    float* lanes   = out + (size_t)M_ * 2;
    float* attn    = out + (size_t)M_ * 2 + (size_t)M_ * ALEN;

    // workspace layout (~215 MB)
    char* w = (char*)d_ws;
    float* feat      = (float*)w;    w += (size_t)B_ * CF * HFM * WFM * 4;       // 512 KB
    ushort_t* pf16   = (ushort_t*)w; w += (size_t)M_ * D_ * 2;                   // 28.5 MB
    ushort_t* pfT16  = (ushort_t*)w; w += (size_t)B_ * D_ * NANCH * 2;           // 28.5 MB
    ushort_t* aw16   = (ushort_t*)w; w += (size_t)NMPAD * D_ * 2;                // 3.6 MB
    ushort_t* att16  = (ushort_t*)w; w += (size_t)M_ * D_ * 2;                   // 28.5 MB
    ushort_t* hw16   = (ushort_t*)w; w += (size_t)128 * D2 * 2;                  // 320 KB
    ushort_t* attn16 = (ushort_t*)w; w += (size_t)(M_ + 32) * NANCH * 2;         // 124.2 MB (+32-row pad)

    conv_feat_k<<<(B_ * CF * HFM * WFM + 255) / 256, 256, 0, stream>>>(x, conv_w, conv_b, feat);
    gather_pf_k<<<(int)(((long long)M_ * D_ + 255) / 256), 256, 0, stream>>>(feat, cut_xs, invalid, pf16);
    gather_pfT_k<<<(int)(((long long)B_ * D_ * NANCH + 255) / 256), 256, 0, stream>>>(feat, cut_xs, invalid, pfT16);
    prep_attn_w_k<<<(NMPAD * D_ + 255) / 256, 256, 0, stream>>>(attn_w, aw16);
    prep_heads_w_k<<<(128 * D2 + 255) / 256, 256, 0, stream>>>(cls_w, reg_w, hw16);

    scores_mfma_k<<<dim3(M_ / 128, NMPAD / 128), 256, 0, stream>>>(pf16, aw16, attn_b, attn16);
    softmax_k<<<M_, 256, 0, stream>>>(attn, attn16);
    att_mfma_k<<<dim3(22 * 5 * B_), 256, 0, stream>>>(attn16, pfT16, att16);
    heads_mfma_k<<<dim3(M_ / 128), 256, 0, stream>>>(att16, pf16, hw16, cls_b, reg_b, anchors, cls_out, lanes);
}